// Round 1
// baseline (188.427 us; speedup 1.0000x reference)
//
#include <hip/hip_runtime.h>
#include <math.h>

#define TLEN 16384
#define MROW 8
#define NPAIR 36   // 8*9/2 symmetric pairs
#define NTHREADS 512
#define EPSV 1e-8f

__global__ __launch_bounds__(NTHREADS)
void ssf_kernel(const float* __restrict__ X, float* __restrict__ out) {
    const int n   = blockIdx.x;
    const int tid = threadIdx.x;
    const float4* Xv = reinterpret_cast<const float4*>(X + (size_t)n * MROW * TLEN);
    const int TV = TLEN / 4;  // 4096 float4 per row

    float acc[NPAIR];
#pragma unroll
    for (int p = 0; p < NPAIR; ++p) acc[p] = 0.f;

    // Stream: each iter loads one float4 from each of the 8 rows at the same
    // column offset (8 outstanding dwordx4, fully coalesced), then 144 FMAs.
    for (int it = tid; it < TV; it += NTHREADS) {
        float4 x[MROW];
#pragma unroll
        for (int m = 0; m < MROW; ++m) x[m] = Xv[m * TV + it];
        const float* xv = reinterpret_cast<const float*>(x);
#pragma unroll
        for (int e = 0; e < 4; ++e) {
            int p = 0;
#pragma unroll
            for (int m = 0; m < MROW; ++m) {
                const float vm = xv[m * 4 + e];
#pragma unroll
                for (int k = m; k < MROW; ++k) {
                    acc[p++] += vm * xv[k * 4 + e];
                }
            }
        }
    }

    // Wave (64-lane) butterfly reduction of each accumulator
#pragma unroll
    for (int p = 0; p < NPAIR; ++p) {
        float v = acc[p];
#pragma unroll
        for (int off = 32; off > 0; off >>= 1) v += __shfl_down(v, off, 64);
        acc[p] = v;
    }

    __shared__ float partial[NTHREADS / 64][NPAIR];
    __shared__ float Cm[MROW][MROW];
    const int wave = tid >> 6;
    const int lane = tid & 63;
    if (lane == 0) {
#pragma unroll
        for (int p = 0; p < NPAIR; ++p) partial[wave][p] = acc[p];
    }
    __syncthreads();

    if (tid < NPAIR) {
        float s = 0.f;
#pragma unroll
        for (int w = 0; w < NTHREADS / 64; ++w) s += partial[w][tid];
        s *= (1.0f / (float)TLEN);
        // decode linear pair index -> (m,k), m<=k
        int p = tid, m = 0;
        while (p >= (MROW - m)) { p -= (MROW - m); ++m; }
        const int k = m + p;
        Cm[m][k] = s;
        Cm[k][m] = s;
    }
    __syncthreads();

    if (tid == 0) {
        // triu_indices(5)
        const int rows[15] = {0,0,0,0,0, 1,1,1,1, 2,2,2, 3,3, 4};
        const int cols[15] = {0,1,2,3,4, 1,2,3,4, 2,3,4, 3,4, 4};
        float tri[15];
        float sum = 0.f;
#pragma unroll
        for (int i = 0; i < 15; ++i) {
            float r = 0.f;
#pragma unroll
            for (int j = 0; j < 4; ++j) r += Cm[j + rows[i]][j + cols[i]];
            r *= 0.25f;   // mean over J=4 diagonal shifts
            tri[i] = r;
            sum += r;
        }
        // feat = [tri(15), zeros(15)]; population mean/std over all 30
        const float mean = sum * (1.0f / 30.0f);
        float var = 0.f;
#pragma unroll
        for (int i = 0; i < 15; ++i) { const float d = tri[i] - mean; var += d * d; }
        var += 15.0f * mean * mean;   // the 15 zero entries
        var *= (1.0f / 30.0f);
        const float inv = 1.0f / (sqrtf(var) + EPSV);

        float* o = out + (size_t)n * 30;
#pragma unroll
        for (int i = 0; i < 15; ++i) o[i] = (tri[i] - mean) * inv;
        const float zi = -mean * inv;
#pragma unroll
        for (int i = 0; i < 15; ++i) o[15 + i] = zi;
    }
}

extern "C" void kernel_launch(void* const* d_in, const int* in_sizes, int n_in,
                              void* d_out, int out_size, void* d_ws, size_t ws_size,
                              hipStream_t stream) {
    const float* X = (const float*)d_in[0];
    float* out = (float*)d_out;
    ssf_kernel<<<256, NTHREADS, 0, stream>>>(X, out);
}

// Round 2
// 187.751 us; speedup vs baseline: 1.0036x; 1.0036x over previous
//
#include <hip/hip_runtime.h>
#include <math.h>

#define TLEN 16384
#define MROW 8
#define NPAIR 30      // pairs (m,k) with m<=k<=min(m+4,7) — only lags 0..4 are consumed
#define NCHUNK 8      // blocks per batch along T
#define NT1 256
#define EPSV 1e-8f

// Kernel 1: partial Gram sums. grid = 256*NCHUNK blocks, NT1 threads.
// Block b handles batch n=b/NCHUNK, column chunk c=b%NCHUNK (512 float4 cols).
__global__ __launch_bounds__(NT1)
void ssf_partial(const float* __restrict__ X, float* __restrict__ part) {
    const int b   = blockIdx.x;
    const int n   = b >> 3;          // NCHUNK == 8
    const int c   = b & 7;
    const int tid = threadIdx.x;
    const int TV  = TLEN / 4;        // 4096 float4 per row
    const int COLS = TV / NCHUNK;    // 512 float4 per chunk
    const float4* Xv = reinterpret_cast<const float4*>(X + (size_t)n * MROW * TLEN);
    const int base = c * COLS;

    float acc[NPAIR];
#pragma unroll
    for (int p = 0; p < NPAIR; ++p) acc[p] = 0.f;

    // trip count = COLS/NT1 = 2 -> fully unrolled, 16 loads in flight
#pragma unroll
    for (int i = 0; i < COLS / NT1; ++i) {
        const int it = base + i * NT1 + tid;
        float4 x[MROW];
#pragma unroll
        for (int m = 0; m < MROW; ++m) x[m] = Xv[m * TV + it];
        const float* xv = reinterpret_cast<const float*>(x);
#pragma unroll
        for (int e = 0; e < 4; ++e) {
            int p = 0;
#pragma unroll
            for (int m = 0; m < MROW; ++m) {
                const float vm = xv[m * 4 + e];
                const int kmax = (m + 4 < MROW - 1) ? m + 4 : MROW - 1;
#pragma unroll
                for (int k = m; k <= kmax; ++k) {
                    acc[p++] += vm * xv[k * 4 + e];
                }
            }
        }
    }

    // 64-lane butterfly reduction per accumulator
#pragma unroll
    for (int p = 0; p < NPAIR; ++p) {
        float v = acc[p];
#pragma unroll
        for (int off = 32; off > 0; off >>= 1) v += __shfl_down(v, off, 64);
        acc[p] = v;
    }

    __shared__ float partial[NT1 / 64][NPAIR];
    const int wave = tid >> 6;
    const int lane = tid & 63;
    if (lane == 0) {
#pragma unroll
        for (int p = 0; p < NPAIR; ++p) partial[wave][p] = acc[p];
    }
    __syncthreads();

    if (tid < NPAIR) {
        float s = 0.f;
#pragma unroll
        for (int w = 0; w < NT1 / 64; ++w) s += partial[w][tid];
        part[(size_t)b * NPAIR + tid] = s;
    }
}

// Kernel 2: reduce NCHUNK partials per batch, build C, epilogue. grid = 256, 64 threads.
__global__ __launch_bounds__(64)
void ssf_final(const float* __restrict__ part, float* __restrict__ out) {
    const int n   = blockIdx.x;
    const int tid = threadIdx.x;
    __shared__ float Cm[MROW][MROW];

    if (tid < NPAIR) {
        float s = 0.f;
#pragma unroll
        for (int c = 0; c < NCHUNK; ++c)
            s += part[((size_t)n * NCHUNK + c) * NPAIR + tid];
        s *= (1.0f / (float)TLEN);
        // decode linear pair index -> (m,k): m<=k<=min(m+4,7)
        int p = tid, m = 0;
        for (;;) {
            const int cnt = ((m + 4 < MROW - 1) ? m + 4 : MROW - 1) - m + 1;
            if (p < cnt) break;
            p -= cnt; ++m;
        }
        const int k = m + p;
        Cm[m][k] = s;
        Cm[k][m] = s;
    }
    __syncthreads();

    if (tid == 0) {
        const int rows[15] = {0,0,0,0,0, 1,1,1,1, 2,2,2, 3,3, 4};
        const int cols[15] = {0,1,2,3,4, 1,2,3,4, 2,3,4, 3,4, 4};
        float tri[15];
        float sum = 0.f;
#pragma unroll
        for (int i = 0; i < 15; ++i) {
            float r = 0.f;
#pragma unroll
            for (int j = 0; j < 4; ++j) r += Cm[j + rows[i]][j + cols[i]];
            r *= 0.25f;   // mean over J=4 shifts
            tri[i] = r;
            sum += r;
        }
        const float mean = sum * (1.0f / 30.0f);
        float var = 0.f;
#pragma unroll
        for (int i = 0; i < 15; ++i) { const float d = tri[i] - mean; var += d * d; }
        var += 15.0f * mean * mean;   // 15 zero imag entries
        var *= (1.0f / 30.0f);
        const float inv = 1.0f / (sqrtf(var) + EPSV);

        float* o = out + (size_t)n * 30;
#pragma unroll
        for (int i = 0; i < 15; ++i) o[i] = (tri[i] - mean) * inv;
        const float zi = -mean * inv;
#pragma unroll
        for (int i = 0; i < 15; ++i) o[15 + i] = zi;
    }
}

extern "C" void kernel_launch(void* const* d_in, const int* in_sizes, int n_in,
                              void* d_out, int out_size, void* d_ws, size_t ws_size,
                              hipStream_t stream) {
    const float* X = (const float*)d_in[0];
    float* out  = (float*)d_out;
    float* part = (float*)d_ws;   // 256*NCHUNK*NPAIR floats = 240 KB
    ssf_partial<<<256 * NCHUNK, NT1, 0, stream>>>(X, part);
    ssf_final<<<256, 64, 0, stream>>>(part, out);
}